// Round 2
// baseline (922.038 us; speedup 1.0000x reference)
//
#include <hip/hip_runtime.h>
#include <hip/hip_bf16.h>
#include <stdint.h>

typedef __bf16 bf16_t;
typedef __bf16 bf16x8 __attribute__((ext_vector_type(8)));
typedef __bf16 bf16x4 __attribute__((ext_vector_type(4)));
typedef float f32x4 __attribute__((ext_vector_type(4)));

// async global->LDS, 16B per lane. LDS dest must be wave-uniform base + lane*16.
__device__ __forceinline__ void gload_lds16(const bf16_t* g, bf16_t* l) {
  __builtin_amdgcn_global_load_lds((const __attribute__((address_space(1))) void*)g,
                                   (__attribute__((address_space(3))) void*)l, 16, 0, 0);
}

// ---------------- fp32 W[k][m] -> bf16 Bt[m][k] (tiled transpose + cast) --------
__global__ __launch_bounds__(256) void transpose_cast_k(const float* __restrict__ W,
                                                        bf16_t* __restrict__ Bt,
                                                        int KDin, int MDin) {
  __shared__ float tile[64][65];
  const int bm = blockIdx.x, bk = blockIdx.y;
  const int c = threadIdx.x & 63, r0 = threadIdx.x >> 6;
#pragma unroll
  for (int rr = 0; rr < 16; ++rr) {
    int row = rr * 4 + r0;
    tile[row][c] = W[(size_t)(bk * 64 + row) * MDin + bm * 64 + c];
  }
  __syncthreads();
#pragma unroll
  for (int rr = 0; rr < 16; ++rr) {
    int mo = rr * 4 + r0;
    Bt[(size_t)(bm * 64 + mo) * KDin + bk * 64 + c] = (bf16_t)tile[c][mo];
  }
}

// ---------------- feat[order[j]] -> bf16 featp[j] ------------------------------
__global__ __launch_bounds__(256) void gather_cast_k(const float* __restrict__ feat,
                                                     const int* __restrict__ order,
                                                     bf16_t* __restrict__ featp) {
  const int id = blockIdx.x * 256 + threadIdx.x;  // 32768*192 total
  const int j = id / 192;
  const int c = (id % 192) * 4;
  const int g = order[j];
  const float4 v = *(const float4*)(feat + (size_t)g * 768 + c);
  bf16x4 o;
  o[0] = (bf16_t)v.x; o[1] = (bf16_t)v.y; o[2] = (bf16_t)v.z; o[3] = (bf16_t)v.w;
  *(bf16x4*)(featp + (size_t)j * 768 + c) = o;
}

// ---------------- GEMM: C[j][m] = A[j][:] . Bt[m][:] + bias[m] -----------------
// A [NR][768] bf16, Bt [MD][768] bf16. 128x128 tile, BK=32, 4 waves (2x2 of 64x64).
// MODE 0: bf16 store split into Cq/Ck/Cv [N][768] by global col / 768.
// MODE 1: fp32 scatter Cf[order[j]][768].
template <int MODE>
__global__ __launch_bounds__(256) void gemm_bt_k(const bf16_t* __restrict__ A,
                                                 const bf16_t* __restrict__ Bt,
                                                 const float* __restrict__ bias,
                                                 bf16_t* __restrict__ Cq,
                                                 bf16_t* __restrict__ Ck,
                                                 bf16_t* __restrict__ Cv,
                                                 float* __restrict__ Cf,
                                                 const int* __restrict__ order) {
  __shared__ bf16_t As[128 * 32];
  __shared__ bf16_t Bs[128 * 32];
  const int tid = threadIdx.x;
  const int lane = tid & 63;
  const int wave = tid >> 6;
  const int wr = wave >> 1, wc = wave & 1;
  const int lq = lane & 15, lk = lane >> 4;
  const int bx = blockIdx.x, by = blockIdx.y;

  const bf16_t* gA = A + (size_t)(by * 128 + (tid >> 2)) * 768 + (tid & 3) * 8;
  const bf16_t* gB = Bt + (size_t)(bx * 128 + (tid >> 2)) * 768 + (tid & 3) * 8;
  bf16_t* lA = As + tid * 8;
  bf16_t* lB = Bs + tid * 8;

  f32x4 acc[4][4] = {};

  for (int kk = 0; kk < 24; ++kk) {
    gload_lds16(gA, lA);
    gload_lds16(gA + 64 * 768, lA + 2048);
    gload_lds16(gB, lB);
    gload_lds16(gB + 64 * 768, lB + 2048);
    gA += 32;
    gB += 32;
    __syncthreads();
    bf16x8 af[4], bfr[4];
#pragma unroll
    for (int t = 0; t < 4; ++t) {
      af[t]  = *(const bf16x8*)(As + (wr * 64 + t * 16 + lq) * 32 + lk * 8);
      bfr[t] = *(const bf16x8*)(Bs + (wc * 64 + t * 16 + lq) * 32 + lk * 8);
    }
#pragma unroll
    for (int mt = 0; mt < 4; ++mt)
#pragma unroll
      for (int nt = 0; nt < 4; ++nt)
        acc[mt][nt] = __builtin_amdgcn_mfma_f32_16x16x32_bf16(af[mt], bfr[nt], acc[mt][nt], 0, 0, 0);
    __syncthreads();
  }

  const int colb = bx * 128 + wc * 64;  // global output column base
  float bcol[4];
#pragma unroll
  for (int nt = 0; nt < 4; ++nt) bcol[nt] = bias[colb + nt * 16 + lq];

#pragma unroll
  for (int mt = 0; mt < 4; ++mt) {
    const int row = by * 128 + wr * 64 + mt * 16 + lk * 4;
    if (MODE == 0) {
      bf16_t* base = (bx < 6) ? Cq : (bx < 12 ? Ck : Cv);
      const int coll = colb - (bx < 6 ? 0 : (bx < 12 ? 768 : 1536));
#pragma unroll
      for (int nt = 0; nt < 4; ++nt) {
        const int col = coll + nt * 16 + lq;
#pragma unroll
        for (int r = 0; r < 4; ++r)
          base[(size_t)(row + r) * 768 + col] = (bf16_t)(acc[mt][nt][r] + bcol[nt]);
      }
    } else {
      int ro[4];
#pragma unroll
      for (int r = 0; r < 4; ++r) ro[r] = order[row + r];
#pragma unroll
      for (int nt = 0; nt < 4; ++nt) {
        const int col = colb + nt * 16 + lq;
#pragma unroll
        for (int r = 0; r < 4; ++r)
          Cf[(size_t)ro[r] * 768 + col] = acc[mt][nt][r] + bcol[nt];
      }
    }
  }
}

// ---------------- RoPE3D on q,k + MFMA-fragment packing of K and V -------------
// Qb roped in place.  Kp[ph][(nt*3+a)*64 + lane][8]: lane = lk*16 + (t&15) holds
// K[nt*16 + (t&15)][a*32 + lk*8 + j]  (B-frag order for S = Q.K^T).
// Vp[ph][(dt*8+kc)*64 + lane][8]: lane = ((t>>3)&3)*16 + (d&15), elem j = t&7
// holds V[token t][d]  (B-frag order for O = P.V).
__global__ __launch_bounds__(256) void rope_pack_k(bf16_t* __restrict__ Qb,
                                                   const bf16_t* __restrict__ Kb,
                                                   const bf16_t* __restrict__ Vb,
                                                   bf16_t* __restrict__ Kp,
                                                   bf16_t* __restrict__ Vp,
                                                   const int* __restrict__ grid_coord,
                                                   const int* __restrict__ order) {
  const int h = blockIdx.x, p = blockIdx.y;
  const int t = threadIdx.x;
  const int j = p * 256 + t;
  const int g = order[j];
  float pos[3];
  pos[0] = (float)grid_coord[g * 3 + 0];
  pos[1] = (float)grid_coord[g * 3 + 1];
  pos[2] = (float)grid_coord[g * 3 + 2];
  bf16_t* qrow = Qb + (size_t)j * 768 + h * 96;
  const bf16_t* krow = Kb + (size_t)j * 768 + h * 96;
  bf16_t* Kps = Kp + (size_t)(p * 8 + h) * 24576;
  const int nt = t >> 4, lqt = t & 15;
  const float NEGL = -0.41524101186f;  // -log2(100)/16
#pragma unroll
  for (int a = 0; a < 3; ++a) {
    const float pa = pos[a];
    bf16x8 q0 = *(bf16x8*)(qrow + a * 32);
    bf16x8 q1 = *(bf16x8*)(qrow + a * 32 + 8);
    bf16x8 q2 = *(bf16x8*)(qrow + a * 32 + 16);
    bf16x8 q3 = *(bf16x8*)(qrow + a * 32 + 24);
    bf16x8 k0 = *(const bf16x8*)(krow + a * 32);
    bf16x8 k1 = *(const bf16x8*)(krow + a * 32 + 8);
    bf16x8 k2 = *(const bf16x8*)(krow + a * 32 + 16);
    bf16x8 k3 = *(const bf16x8*)(krow + a * 32 + 24);
    float s[16], c[16];
#pragma unroll
    for (int i = 0; i < 16; ++i) {
      float ang = pa * exp2f(NEGL * (float)i);
      __sincosf(ang, &s[i], &c[i]);
    }
#pragma unroll
    for (int i = 0; i < 8; ++i) {
      float x1 = (float)q0[i], x2 = (float)q2[i];
      q0[i] = (bf16_t)(x1 * c[i] - x2 * s[i]);
      q2[i] = (bf16_t)(x1 * s[i] + x2 * c[i]);
      float y1 = (float)q1[i], y2 = (float)q3[i];
      q1[i] = (bf16_t)(y1 * c[i + 8] - y2 * s[i + 8]);
      q3[i] = (bf16_t)(y1 * s[i + 8] + y2 * c[i + 8]);
      float u1 = (float)k0[i], u2 = (float)k2[i];
      k0[i] = (bf16_t)(u1 * c[i] - u2 * s[i]);
      k2[i] = (bf16_t)(u1 * s[i] + u2 * c[i]);
      float w1 = (float)k1[i], w2 = (float)k3[i];
      k1[i] = (bf16_t)(w1 * c[i + 8] - w2 * s[i + 8]);
      k3[i] = (bf16_t)(w1 * s[i + 8] + w2 * c[i + 8]);
    }
    *(bf16x8*)(qrow + a * 32) = q0;
    *(bf16x8*)(qrow + a * 32 + 8) = q1;
    *(bf16x8*)(qrow + a * 32 + 16) = q2;
    *(bf16x8*)(qrow + a * 32 + 24) = q3;
    bf16_t* kf = Kps + (size_t)((nt * 3 + a) * 64 + lqt) * 8;
    *(bf16x8*)(kf)           = k0;   // lk=0: feats a*32 + 0..7
    *(bf16x8*)(kf + 16 * 8)  = k1;   // lk=1
    *(bf16x8*)(kf + 32 * 8)  = k2;   // lk=2
    *(bf16x8*)(kf + 48 * 8)  = k3;   // lk=3
  }
  // V fragment pack
  const bf16_t* vrow = Vb + (size_t)j * 768 + h * 96;
  bf16_t* Vps = Vp + (size_t)(p * 8 + h) * 24576;
  const int kc8 = t >> 5, lkv = (t >> 3) & 3, jv = t & 7;
#pragma unroll
  for (int d0 = 0; d0 < 96; d0 += 8) {
    bf16x8 v = *(const bf16x8*)(vrow + d0);
    const int dt = d0 >> 4;
    bf16_t* vf = Vps + (size_t)((dt * 8 + kc8) * 64 + lkv * 16 + (d0 & 15)) * 8 + jv;
#pragma unroll
    for (int i = 0; i < 8; ++i) vf[i * 8] = v[i];
  }
}

// ---------------- windowed attention (v3: frag-packed K/V, in-place over Q) ----
// grid = 1024 (p,h) blocks; 4 waves, each owns 64 q-rows, processed as 2 pairs
// of 16-row tiles (shared K/V frag loads across the pair).  P transposed through
// a per-wave XOR-swizzled LDS buffer (conflict-free, 64 KB total).
__global__ __launch_bounds__(256, 2) void attn_k(bf16_t* QO,   // Q in, O out (same buffer)
                                                 const bf16_t* __restrict__ Kp,
                                                 const bf16_t* __restrict__ Vp) {
  __shared__ bf16_t P[4][2][4096];  // [wave][m][16 rows x 256, swizzled] = 65536 B
  const int ph = blockIdx.x;
  const int h = ph & 7, p = ph >> 3;
  const int tid = threadIdx.x, lane = tid & 63, wave = tid >> 6;
  const int lq = lane & 15, lk = lane >> 4;
  const int tok0 = p * 256, qr0 = wave * 64;
  const bf16_t* Kps = Kp + (size_t)ph * 24576;
  const bf16_t* Vps = Vp + (size_t)ph * 24576;
  const float scale = 0.10206207262f;  // 96^-0.5

  for (int pair = 0; pair < 2; ++pair) {
    // ---- Q fragments for the two 16-row tiles of this pair
    bf16x8 aq[2][3];
#pragma unroll
    for (int m = 0; m < 2; ++m) {
      const bf16_t* qb = QO + (size_t)(tok0 + qr0 + pair * 32 + m * 16 + lq) * 768 + h * 96 + lk * 8;
#pragma unroll
      for (int kc = 0; kc < 3; ++kc) aq[m][kc] = *(const bf16x8*)(qb + kc * 32);
    }

    // ---- S = Q.K^T  (coalesced 1KB frag loads, shared across the pair)
    f32x4 sacc[2][16] = {};
#pragma unroll
    for (int nt = 0; nt < 16; ++nt) {
#pragma unroll
      for (int kc = 0; kc < 3; ++kc) {
        bf16x8 bk = *(const bf16x8*)(Kps + (size_t)((nt * 3 + kc) * 64 + lane) * 8);
        sacc[0][nt] = __builtin_amdgcn_mfma_f32_16x16x32_bf16(aq[0][kc], bk, sacc[0][nt], 0, 0, 0);
        sacc[1][nt] = __builtin_amdgcn_mfma_f32_16x16x32_bf16(aq[1][kc], bk, sacc[1][nt], 0, 0, 0);
      }
    }

    // ---- softmax (rows live in C-layout: row = lk*4+r, col = nt*16+lq)
    float linv[2][4];
#pragma unroll
    for (int m = 0; m < 2; ++m) {
#pragma unroll
      for (int r = 0; r < 4; ++r) {
        float mx = -1e30f;
#pragma unroll
        for (int nt = 0; nt < 16; ++nt) mx = fmaxf(mx, sacc[m][nt][r]);
        mx = fmaxf(mx, __shfl_xor(mx, 1));
        mx = fmaxf(mx, __shfl_xor(mx, 2));
        mx = fmaxf(mx, __shfl_xor(mx, 4));
        mx = fmaxf(mx, __shfl_xor(mx, 8));
        mx *= scale;
        float l = 0.f;
#pragma unroll
        for (int nt = 0; nt < 16; ++nt) {
          float e = __expf(sacc[m][nt][r] * scale - mx);
          sacc[m][nt][r] = e;
          l += e;
        }
        l += __shfl_xor(l, 1);
        l += __shfl_xor(l, 2);
        l += __shfl_xor(l, 4);
        l += __shfl_xor(l, 8);
        linv[m][r] = 1.f / l;
      }
    }

    // ---- P -> swizzled LDS (C-layout write, conflict-free)
    bf16_t* P0 = &P[wave][0][0];
    bf16_t* P1 = &P[wave][1][0];
#pragma unroll
    for (int nt = 0; nt < 16; ++nt) {
#pragma unroll
      for (int r = 0; r < 4; ++r) {
        const int row16 = lk * 4 + r;
        const int phys = (nt * 2 + (lq >> 3)) ^ (row16 & 7);
        const int off = row16 * 256 + phys * 8 + (lq & 7);
        P0[off] = (bf16_t)sacc[0][nt][r];
        P1[off] = (bf16_t)sacc[1][nt][r];
      }
    }

    // ---- O = P.V  (A-frags from swizzled LDS, V frags coalesced from Vp)
    f32x4 oacc[2][6] = {};
#pragma unroll
    for (int kc = 0; kc < 8; ++kc) {
      const int phys = (kc * 4 + lk) ^ (lq & 7);
      bf16x8 pf0 = *(const bf16x8*)(P0 + lq * 256 + phys * 8);
      bf16x8 pf1 = *(const bf16x8*)(P1 + lq * 256 + phys * 8);
#pragma unroll
      for (int dt = 0; dt < 6; ++dt) {
        bf16x8 vb = *(const bf16x8*)(Vps + (size_t)((dt * 8 + kc) * 64 + lane) * 8);
        oacc[0][dt] = __builtin_amdgcn_mfma_f32_16x16x32_bf16(pf0, vb, oacc[0][dt], 0, 0, 0);
        oacc[1][dt] = __builtin_amdgcn_mfma_f32_16x16x32_bf16(pf1, vb, oacc[1][dt], 0, 0, 0);
      }
    }

    // ---- write O over Q (same rows this wave read; safe in-place)
#pragma unroll
    for (int m = 0; m < 2; ++m) {
#pragma unroll
      for (int dt = 0; dt < 6; ++dt) {
#pragma unroll
        for (int r = 0; r < 4; ++r) {
          const int row = tok0 + qr0 + pair * 32 + m * 16 + lk * 4 + r;
          QO[(size_t)row * 768 + h * 96 + dt * 16 + lq] = (bf16_t)(oacc[m][dt][r] * linv[m][r]);
        }
      }
    }
  }
}

extern "C" void kernel_launch(void* const* d_in, const int* in_sizes, int n_in,
                              void* d_out, int out_size, void* d_ws, size_t ws_size,
                              hipStream_t stream) {
  const float* feat       = (const float*)d_in[0];
  const int*   grid_coord = (const int*)d_in[1];
  const int*   order      = (const int*)d_in[2];
  // d_in[3] = inverse (unused: scatter-by-order is equivalent)
  const float* w_qkv      = (const float*)d_in[4];
  const float* b_qkv      = (const float*)d_in[5];
  const float* w_proj     = (const float*)d_in[6];
  const float* b_proj     = (const float*)d_in[7];
  float* out = (float*)d_out;

  char* ws = (char*)d_ws;
  bf16_t* Bt1   = (bf16_t*)(ws);                 // 2304x768  bf16  (3,538,944 B)
  bf16_t* Bt2   = (bf16_t*)(ws + 3538944);       // 768x768   bf16  (1,179,648 B)
  bf16_t* featp = (bf16_t*)(ws + 4718592);       // 32768x768 bf16  (50,331,648 B)
  bf16_t* Kp    = featp;                         // featp dead after gemm1; reuse for Kp
  bf16_t* Qb    = (bf16_t*)(ws + 55050240);      // 32768x768 bf16
  bf16_t* Kb    = (bf16_t*)(ws + 105381888);     // 32768x768 bf16
  bf16_t* Vb    = (bf16_t*)(ws + 155713536);     // 32768x768 bf16
  bf16_t* Vp    = (bf16_t*)(ws + 206045184);     // 1024x24576 bf16 (50,331,648 B) -> total 256,376,832

  transpose_cast_k<<<dim3(36, 12), 256, 0, stream>>>(w_qkv, Bt1, 768, 2304);
  transpose_cast_k<<<dim3(12, 12), 256, 0, stream>>>(w_proj, Bt2, 768, 768);
  gather_cast_k<<<24576, 256, 0, stream>>>(feat, order, featp);
  gemm_bt_k<0><<<dim3(18, 256), 256, 0, stream>>>(featp, Bt1, b_qkv, Qb, Kb, Vb, nullptr, nullptr);
  rope_pack_k<<<dim3(8, 128), 256, 0, stream>>>(Qb, Kb, Vb, Kp, Vp, grid_coord, order);
  attn_k<<<1024, 256, 0, stream>>>(Qb, Kp, Vp);
  gemm_bt_k<1><<<dim3(6, 256), 256, 0, stream>>>(Qb, Bt2, b_proj, nullptr, nullptr, nullptr, out, order);
}

// Round 3
// 560.599 us; speedup vs baseline: 1.6447x; 1.6447x over previous
//
#include <hip/hip_runtime.h>
#include <hip/hip_bf16.h>
#include <stdint.h>

typedef __bf16 bf16_t;
typedef __bf16 bf16x8 __attribute__((ext_vector_type(8)));
typedef __bf16 bf16x4 __attribute__((ext_vector_type(4)));
typedef float f32x4 __attribute__((ext_vector_type(4)));

// async global->LDS, 16B per lane. LDS dest must be wave-uniform base + lane*16.
__device__ __forceinline__ void gload_lds16(const bf16_t* g, bf16_t* l) {
  __builtin_amdgcn_global_load_lds((const __attribute__((address_space(1))) void*)g,
                                   (__attribute__((address_space(3))) void*)l, 16, 0, 0);
}

// ---------------- fp32 W[k][m] -> bf16 Bt[m][k] (tiled transpose + cast) --------
__global__ __launch_bounds__(256) void transpose_cast_k(const float* __restrict__ W,
                                                        bf16_t* __restrict__ Bt,
                                                        int KDin, int MDin) {
  __shared__ float tile[64][65];
  const int bm = blockIdx.x, bk = blockIdx.y;
  const int c = threadIdx.x & 63, r0 = threadIdx.x >> 6;
#pragma unroll
  for (int rr = 0; rr < 16; ++rr) {
    int row = rr * 4 + r0;
    tile[row][c] = W[(size_t)(bk * 64 + row) * MDin + bm * 64 + c];
  }
  __syncthreads();
#pragma unroll
  for (int rr = 0; rr < 16; ++rr) {
    int mo = rr * 4 + r0;
    Bt[(size_t)(bm * 64 + mo) * KDin + bk * 64 + c] = (bf16_t)tile[c][mo];
  }
}

// ---------------- feat[order[j]] -> bf16 featp[j] ------------------------------
__global__ __launch_bounds__(256) void gather_cast_k(const float* __restrict__ feat,
                                                     const int* __restrict__ order,
                                                     bf16_t* __restrict__ featp) {
  const int id = blockIdx.x * 256 + threadIdx.x;  // 32768*192 total
  const int j = id / 192;
  const int c = (id % 192) * 4;
  const int g = order[j];
  const float4 v = *(const float4*)(feat + (size_t)g * 768 + c);
  bf16x4 o;
  o[0] = (bf16_t)v.x; o[1] = (bf16_t)v.y; o[2] = (bf16_t)v.z; o[3] = (bf16_t)v.w;
  *(bf16x4*)(featp + (size_t)j * 768 + c) = o;
}

// ---------------- GEMM: C[j][m] = A[j][:] . Bt[m][:] + bias[m] -----------------
// A [NR][768] bf16, Bt [MD][768] bf16. 128x128 tile, BK=32, 4 waves (2x2 of 64x64).
// MODE 0: bf16 store split into Cq/Ck/Cv [N][768] by global col / 768.
// MODE 1: fp32 scatter Cf[order[j]][768].
template <int MODE>
__global__ __launch_bounds__(256) void gemm_bt_k(const bf16_t* __restrict__ A,
                                                 const bf16_t* __restrict__ Bt,
                                                 const float* __restrict__ bias,
                                                 bf16_t* __restrict__ Cq,
                                                 bf16_t* __restrict__ Ck,
                                                 bf16_t* __restrict__ Cv,
                                                 float* __restrict__ Cf,
                                                 const int* __restrict__ order) {
  __shared__ bf16_t As[128 * 32];
  __shared__ bf16_t Bs[128 * 32];
  const int tid = threadIdx.x;
  const int lane = tid & 63;
  const int wave = tid >> 6;
  const int wr = wave >> 1, wc = wave & 1;
  const int lq = lane & 15, lk = lane >> 4;
  const int bx = blockIdx.x, by = blockIdx.y;

  const bf16_t* gA = A + (size_t)(by * 128 + (tid >> 2)) * 768 + (tid & 3) * 8;
  const bf16_t* gB = Bt + (size_t)(bx * 128 + (tid >> 2)) * 768 + (tid & 3) * 8;
  bf16_t* lA = As + tid * 8;
  bf16_t* lB = Bs + tid * 8;

  f32x4 acc[4][4] = {};

  for (int kk = 0; kk < 24; ++kk) {
    gload_lds16(gA, lA);
    gload_lds16(gA + 64 * 768, lA + 2048);
    gload_lds16(gB, lB);
    gload_lds16(gB + 64 * 768, lB + 2048);
    gA += 32;
    gB += 32;
    __syncthreads();
    bf16x8 af[4], bfr[4];
#pragma unroll
    for (int t = 0; t < 4; ++t) {
      af[t]  = *(const bf16x8*)(As + (wr * 64 + t * 16 + lq) * 32 + lk * 8);
      bfr[t] = *(const bf16x8*)(Bs + (wc * 64 + t * 16 + lq) * 32 + lk * 8);
    }
#pragma unroll
    for (int mt = 0; mt < 4; ++mt)
#pragma unroll
      for (int nt = 0; nt < 4; ++nt)
        acc[mt][nt] = __builtin_amdgcn_mfma_f32_16x16x32_bf16(af[mt], bfr[nt], acc[mt][nt], 0, 0, 0);
    __syncthreads();
  }

  const int colb = bx * 128 + wc * 64;  // global output column base
  float bcol[4];
#pragma unroll
  for (int nt = 0; nt < 4; ++nt) bcol[nt] = bias[colb + nt * 16 + lq];

#pragma unroll
  for (int mt = 0; mt < 4; ++mt) {
    const int row = by * 128 + wr * 64 + mt * 16 + lk * 4;
    if (MODE == 0) {
      bf16_t* base = (bx < 6) ? Cq : (bx < 12 ? Ck : Cv);
      const int coll = colb - (bx < 6 ? 0 : (bx < 12 ? 768 : 1536));
#pragma unroll
      for (int nt = 0; nt < 4; ++nt) {
        const int col = coll + nt * 16 + lq;
#pragma unroll
        for (int r = 0; r < 4; ++r)
          base[(size_t)(row + r) * 768 + col] = (bf16_t)(acc[mt][nt][r] + bcol[nt]);
      }
    } else {
      int ro[4];
#pragma unroll
      for (int r = 0; r < 4; ++r) ro[r] = order[row + r];
#pragma unroll
      for (int nt = 0; nt < 4; ++nt) {
        const int col = colb + nt * 16 + lq;
#pragma unroll
        for (int r = 0; r < 4; ++r)
          Cf[(size_t)ro[r] * 768 + col] = acc[mt][nt][r] + bcol[nt];
      }
    }
  }
}

// ---------------- RoPE3D on q,k + MFMA-fragment packing of K and V -------------
// Qb roped in place.  Kp[ph][(nt*3+a)*64 + lane][8]: lane = lk*16 + (t&15) holds
// K[nt*16 + (t&15)][a*32 + lk*8 + j]  (B-frag order for S = Q.K^T).
// Vp[ph][(dt*8+kc)*64 + lane][8]: lane = ((t>>3)&3)*16 + (d&15), elem j = t&7
// holds V[token t][d]  (B-frag order for O = P.V).
__global__ __launch_bounds__(256) void rope_pack_k(bf16_t* __restrict__ Qb,
                                                   const bf16_t* __restrict__ Kb,
                                                   const bf16_t* __restrict__ Vb,
                                                   bf16_t* __restrict__ Kp,
                                                   bf16_t* __restrict__ Vp,
                                                   const int* __restrict__ grid_coord,
                                                   const int* __restrict__ order) {
  const int h = blockIdx.x, p = blockIdx.y;
  const int t = threadIdx.x;
  const int j = p * 256 + t;
  const int g = order[j];
  float pos[3];
  pos[0] = (float)grid_coord[g * 3 + 0];
  pos[1] = (float)grid_coord[g * 3 + 1];
  pos[2] = (float)grid_coord[g * 3 + 2];
  bf16_t* qrow = Qb + (size_t)j * 768 + h * 96;
  const bf16_t* krow = Kb + (size_t)j * 768 + h * 96;
  bf16_t* Kps = Kp + (size_t)(p * 8 + h) * 24576;
  const int nt = t >> 4, lqt = t & 15;
  const float NEGL = -0.41524101186f;  // -log2(100)/16
#pragma unroll
  for (int a = 0; a < 3; ++a) {
    const float pa = pos[a];
    bf16x8 q0 = *(bf16x8*)(qrow + a * 32);
    bf16x8 q1 = *(bf16x8*)(qrow + a * 32 + 8);
    bf16x8 q2 = *(bf16x8*)(qrow + a * 32 + 16);
    bf16x8 q3 = *(bf16x8*)(qrow + a * 32 + 24);
    bf16x8 k0 = *(const bf16x8*)(krow + a * 32);
    bf16x8 k1 = *(const bf16x8*)(krow + a * 32 + 8);
    bf16x8 k2 = *(const bf16x8*)(krow + a * 32 + 16);
    bf16x8 k3 = *(const bf16x8*)(krow + a * 32 + 24);
    float s[16], c[16];
#pragma unroll
    for (int i = 0; i < 16; ++i) {
      float ang = pa * exp2f(NEGL * (float)i);
      __sincosf(ang, &s[i], &c[i]);
    }
#pragma unroll
    for (int i = 0; i < 8; ++i) {
      float x1 = (float)q0[i], x2 = (float)q2[i];
      q0[i] = (bf16_t)(x1 * c[i] - x2 * s[i]);
      q2[i] = (bf16_t)(x1 * s[i] + x2 * c[i]);
      float y1 = (float)q1[i], y2 = (float)q3[i];
      q1[i] = (bf16_t)(y1 * c[i + 8] - y2 * s[i + 8]);
      q3[i] = (bf16_t)(y1 * s[i + 8] + y2 * c[i + 8]);
      float u1 = (float)k0[i], u2 = (float)k2[i];
      k0[i] = (bf16_t)(u1 * c[i] - u2 * s[i]);
      k2[i] = (bf16_t)(u1 * s[i] + u2 * c[i]);
      float w1 = (float)k1[i], w2 = (float)k3[i];
      k1[i] = (bf16_t)(w1 * c[i + 8] - w2 * s[i + 8]);
      k3[i] = (bf16_t)(w1 * s[i + 8] + w2 * c[i + 8]);
    }
    *(bf16x8*)(qrow + a * 32) = q0;
    *(bf16x8*)(qrow + a * 32 + 8) = q1;
    *(bf16x8*)(qrow + a * 32 + 16) = q2;
    *(bf16x8*)(qrow + a * 32 + 24) = q3;
    bf16_t* kf = Kps + (size_t)((nt * 3 + a) * 64 + lqt) * 8;
    *(bf16x8*)(kf)           = k0;   // lk=0: feats a*32 + 0..7
    *(bf16x8*)(kf + 16 * 8)  = k1;   // lk=1
    *(bf16x8*)(kf + 32 * 8)  = k2;   // lk=2
    *(bf16x8*)(kf + 48 * 8)  = k3;   // lk=3
  }
  // V fragment pack
  const bf16_t* vrow = Vb + (size_t)j * 768 + h * 96;
  bf16_t* Vps = Vp + (size_t)(p * 8 + h) * 24576;
  const int kc8 = t >> 5, lkv = (t >> 3) & 3, jv = t & 7;
#pragma unroll
  for (int d0 = 0; d0 < 96; d0 += 8) {
    bf16x8 v = *(const bf16x8*)(vrow + d0);
    const int dt = d0 >> 4;
    bf16_t* vf = Vps + (size_t)((dt * 8 + kc8) * 64 + lkv * 16 + (d0 & 15)) * 8 + jv;
#pragma unroll
    for (int i = 0; i < 8; ++i) vf[i * 8] = v[i];
  }
}

// ---------------- windowed attention (v4: LDS-staged K then V) -----------------
// grid = ph*4 chunks; block = 4 waves, each owns 16 q-rows of one (p,h).
// Stage Kp slice (48KB) -> LDS, S from ds_read_b128; barrier; restage Vp slice
// into the SAME 48KB (overlapped with softmax); PV through a per-wave PRIVATE
// 4KB XOR-swizzled P buffer in two 128-token halves.  LDS = 64KB exactly.
__global__ __launch_bounds__(256) void attn_k(bf16_t* QO,   // Q in, O out (same buffer)
                                              const bf16_t* __restrict__ Kp,
                                              const bf16_t* __restrict__ Vp) {
  __shared__ bf16_t KV[24576];     // 48KB: K frags, then V frags
  __shared__ bf16_t Pb[4][2048];   // 16KB: per-wave swizzled 16x128 P half
  const int bid = blockIdx.x;
  const int chunk = bid & 3;
  const int ph = bid >> 2;
  const int h = ph & 7, p = ph >> 3;
  const int tid = threadIdx.x, lane = tid & 63, wave = tid >> 6;
  const int lq = lane & 15, lk = lane >> 4;
  const int tok0 = p * 256;
  const int qrow0 = chunk * 64 + wave * 16;
  const bf16_t* Kps = Kp + (size_t)ph * 24576;
  const bf16_t* Vps = Vp + (size_t)ph * 24576;
  const float scale = 0.10206207262f;  // 96^-0.5

  // ---- stage K frags (48KB) async; Q frag loads overlap
#pragma unroll
  for (int i = 0; i < 12; ++i)
    gload_lds16(Kps + i * 2048 + tid * 8, KV + i * 2048 + tid * 8);
  bf16x8 aq[3];
  {
    const bf16_t* qb = QO + (size_t)(tok0 + qrow0 + lq) * 768 + h * 96 + lk * 8;
#pragma unroll
    for (int kc = 0; kc < 3; ++kc) aq[kc] = *(const bf16x8*)(qb + kc * 32);
  }
  __syncthreads();

  // ---- S = Q.K^T from LDS
  f32x4 sacc[16];
#pragma unroll
  for (int nt = 0; nt < 16; ++nt) {
    f32x4 acc = {0.f, 0.f, 0.f, 0.f};
#pragma unroll
    for (int kc = 0; kc < 3; ++kc) {
      bf16x8 bk = *(const bf16x8*)(KV + (size_t)((nt * 3 + kc) * 64 + lane) * 8);
      acc = __builtin_amdgcn_mfma_f32_16x16x32_bf16(aq[kc], bk, acc, 0, 0, 0);
    }
    sacc[nt] = acc;
  }
  __syncthreads();   // all waves done reading K from LDS

  // ---- restage V frags into same LDS (async; overlaps softmax VALU)
#pragma unroll
  for (int i = 0; i < 12; ++i)
    gload_lds16(Vps + i * 2048 + tid * 8, KV + i * 2048 + tid * 8);

  // ---- softmax (rows in C-layout: row = lk*4+r, col = nt*16+lq)
  float linv[4];
#pragma unroll
  for (int r = 0; r < 4; ++r) {
    float mx = -1e30f;
#pragma unroll
    for (int nt = 0; nt < 16; ++nt) mx = fmaxf(mx, sacc[nt][r]);
    mx = fmaxf(mx, __shfl_xor(mx, 1));
    mx = fmaxf(mx, __shfl_xor(mx, 2));
    mx = fmaxf(mx, __shfl_xor(mx, 4));
    mx = fmaxf(mx, __shfl_xor(mx, 8));
    mx *= scale;
    float l = 0.f;
#pragma unroll
    for (int nt = 0; nt < 16; ++nt) {
      float e = __expf(sacc[nt][r] * scale - mx);
      sacc[nt][r] = e;
      l += e;
    }
    l += __shfl_xor(l, 1);
    l += __shfl_xor(l, 2);
    l += __shfl_xor(l, 4);
    l += __shfl_xor(l, 8);
    linv[r] = 1.f / l;
  }
  __syncthreads();   // V staged

  // ---- PV in two 128-token halves through private swizzled P buffer.
  // Same-wave DS ops are in-order, so no barrier needed around Pb.
  bf16_t* pw = &Pb[wave][0];
  f32x4 oacc[6] = {};
#pragma unroll
  for (int hf = 0; hf < 2; ++hf) {
#pragma unroll
    for (int ntl = 0; ntl < 8; ++ntl) {
      const int nt = hf * 8 + ntl;
      const int chk = ntl * 2 + (lq >> 3);
#pragma unroll
      for (int r = 0; r < 4; ++r) {
        const int row = lk * 4 + r;
        const int phys = chk ^ (row & 7);
        pw[row * 128 + phys * 8 + (lq & 7)] = (bf16_t)sacc[nt][r];
      }
    }
#pragma unroll
    for (int kcl = 0; kcl < 4; ++kcl) {
      const int physr = (kcl * 4 + lk) ^ (lq & 7);
      bf16x8 pf = *(const bf16x8*)(pw + lq * 128 + physr * 8);
      const int kc = hf * 4 + kcl;
#pragma unroll
      for (int dt = 0; dt < 6; ++dt) {
        bf16x8 vb = *(const bf16x8*)(KV + (size_t)((dt * 8 + kc) * 64 + lane) * 8);
        oacc[dt] = __builtin_amdgcn_mfma_f32_16x16x32_bf16(pf, vb, oacc[dt], 0, 0, 0);
      }
    }
  }

  // ---- write O over Q (same rows this wave read; safe in-place)
#pragma unroll
  for (int dt = 0; dt < 6; ++dt) {
#pragma unroll
    for (int r = 0; r < 4; ++r) {
      const int row = tok0 + qrow0 + lk * 4 + r;
      QO[(size_t)row * 768 + h * 96 + dt * 16 + lq] = (bf16_t)(oacc[dt][r] * linv[r]);
    }
  }
}

extern "C" void kernel_launch(void* const* d_in, const int* in_sizes, int n_in,
                              void* d_out, int out_size, void* d_ws, size_t ws_size,
                              hipStream_t stream) {
  const float* feat       = (const float*)d_in[0];
  const int*   grid_coord = (const int*)d_in[1];
  const int*   order      = (const int*)d_in[2];
  // d_in[3] = inverse (unused: scatter-by-order is equivalent)
  const float* w_qkv      = (const float*)d_in[4];
  const float* b_qkv      = (const float*)d_in[5];
  const float* w_proj     = (const float*)d_in[6];
  const float* b_proj     = (const float*)d_in[7];
  float* out = (float*)d_out;

  char* ws = (char*)d_ws;
  bf16_t* Bt1   = (bf16_t*)(ws);                 // 2304x768  bf16  (3,538,944 B)
  bf16_t* Bt2   = (bf16_t*)(ws + 3538944);       // 768x768   bf16  (1,179,648 B)
  bf16_t* featp = (bf16_t*)(ws + 4718592);       // 32768x768 bf16  (50,331,648 B)
  bf16_t* Kp    = featp;                         // featp dead after gemm1; reuse for Kp
  bf16_t* Qb    = (bf16_t*)(ws + 55050240);      // 32768x768 bf16
  bf16_t* Kb    = (bf16_t*)(ws + 105381888);     // 32768x768 bf16
  bf16_t* Vb    = (bf16_t*)(ws + 155713536);     // 32768x768 bf16
  bf16_t* Vp    = (bf16_t*)(ws + 206045184);     // 1024x24576 bf16 (50,331,648 B) -> total 256,376,832

  transpose_cast_k<<<dim3(36, 12), 256, 0, stream>>>(w_qkv, Bt1, 768, 2304);
  transpose_cast_k<<<dim3(12, 12), 256, 0, stream>>>(w_proj, Bt2, 768, 768);
  gather_cast_k<<<24576, 256, 0, stream>>>(feat, order, featp);
  gemm_bt_k<0><<<dim3(18, 256), 256, 0, stream>>>(featp, Bt1, b_qkv, Qb, Kb, Vb, nullptr, nullptr);
  rope_pack_k<<<dim3(8, 128), 256, 0, stream>>>(Qb, Kb, Vb, Kp, Vp, grid_coord, order);
  attn_k<<<4096, 256, 0, stream>>>(Qb, Kp, Vp);
  gemm_bt_k<1><<<dim3(6, 256), 256, 0, stream>>>(Qb, Bt2, b_proj, nullptr, nullptr, nullptr, out, order);
}

// Round 4
// 523.609 us; speedup vs baseline: 1.7609x; 1.0706x over previous
//
#include <hip/hip_runtime.h>
#include <hip/hip_bf16.h>
#include <stdint.h>

typedef __bf16 bf16_t;
typedef __bf16 bf16x8 __attribute__((ext_vector_type(8)));
typedef __bf16 bf16x4 __attribute__((ext_vector_type(4)));
typedef float f32x4 __attribute__((ext_vector_type(4)));

// async global->LDS, 16B per lane. LDS dest must be wave-uniform base + lane*16.
__device__ __forceinline__ void gload_lds16(const bf16_t* g, bf16_t* l) {
  __builtin_amdgcn_global_load_lds((const __attribute__((address_space(1))) void*)g,
                                   (__attribute__((address_space(3))) void*)l, 16, 0, 0);
}

// ---------------- fp32 W[k][m] -> bf16 Bt[m][k] (tiled transpose + cast) --------
__global__ __launch_bounds__(256) void transpose_cast_k(const float* __restrict__ W,
                                                        bf16_t* __restrict__ Bt,
                                                        int KDin, int MDin) {
  __shared__ float tile[64][65];
  const int bm = blockIdx.x, bk = blockIdx.y;
  const int c = threadIdx.x & 63, r0 = threadIdx.x >> 6;
#pragma unroll
  for (int rr = 0; rr < 16; ++rr) {
    int row = rr * 4 + r0;
    tile[row][c] = W[(size_t)(bk * 64 + row) * MDin + bm * 64 + c];
  }
  __syncthreads();
#pragma unroll
  for (int rr = 0; rr < 16; ++rr) {
    int mo = rr * 4 + r0;
    Bt[(size_t)(bm * 64 + mo) * KDin + bk * 64 + c] = (bf16_t)tile[c][mo];
  }
}

// ---------------- feat[order[j]] -> bf16 featp[j]; also emit posf[j][3] --------
__global__ __launch_bounds__(256) void gather_cast_k(const float* __restrict__ feat,
                                                     const int* __restrict__ order,
                                                     const int* __restrict__ grid_coord,
                                                     bf16_t* __restrict__ featp,
                                                     float* __restrict__ posf) {
  const int id = blockIdx.x * 256 + threadIdx.x;  // 32768*192 total
  const int j = id / 192;
  const int c = (id % 192) * 4;
  const int g = order[j];
  const float4 v = *(const float4*)(feat + (size_t)g * 768 + c);
  bf16x4 o;
  o[0] = (bf16_t)v.x; o[1] = (bf16_t)v.y; o[2] = (bf16_t)v.z; o[3] = (bf16_t)v.w;
  *(bf16x4*)(featp + (size_t)j * 768 + c) = o;
  if (c == 0) {
    posf[j * 3 + 0] = (float)grid_coord[g * 3 + 0];
    posf[j * 3 + 1] = (float)grid_coord[g * 3 + 1];
    posf[j * 3 + 2] = (float)grid_coord[g * 3 + 2];
  }
}

// ---------------- GEMM: C[j][m] = A[j][:] . Bt[m][:] + bias[m] -----------------
// A [NR][768] bf16, Bt [MD][768] bf16. 128x128 tile, BK=32, 4 waves (2x2 of 64x64).
// MODE 0: bf16 store split into Cq/Ck/Cv [N][768]; RoPE applied in-epilogue to
//         Q and K sections (pairs nt0/nt1 and nt2/nt3 are the rotation partners).
// MODE 1: fp32 scatter Cf[order[j]][768].
template <int MODE>
__global__ __launch_bounds__(256) void gemm_bt_k(const bf16_t* __restrict__ A,
                                                 const bf16_t* __restrict__ Bt,
                                                 const float* __restrict__ bias,
                                                 bf16_t* __restrict__ Cq,
                                                 bf16_t* __restrict__ Ck,
                                                 bf16_t* __restrict__ Cv,
                                                 float* __restrict__ Cf,
                                                 const int* __restrict__ order,
                                                 const float* __restrict__ posf) {
  __shared__ bf16_t As[128 * 32];
  __shared__ bf16_t Bs[128 * 32];
  const int tid = threadIdx.x;
  const int lane = tid & 63;
  const int wave = tid >> 6;
  const int wr = wave >> 1, wc = wave & 1;
  const int lq = lane & 15, lk = lane >> 4;
  const int bx = blockIdx.x, by = blockIdx.y;

  const bf16_t* gA = A + (size_t)(by * 128 + (tid >> 2)) * 768 + (tid & 3) * 8;
  const bf16_t* gB = Bt + (size_t)(bx * 128 + (tid >> 2)) * 768 + (tid & 3) * 8;
  bf16_t* lA = As + tid * 8;
  bf16_t* lB = Bs + tid * 8;

  f32x4 acc[4][4] = {};

  for (int kk = 0; kk < 24; ++kk) {
    gload_lds16(gA, lA);
    gload_lds16(gA + 64 * 768, lA + 2048);
    gload_lds16(gB, lB);
    gload_lds16(gB + 64 * 768, lB + 2048);
    gA += 32;
    gB += 32;
    __syncthreads();
    bf16x8 af[4], bfr[4];
#pragma unroll
    for (int t = 0; t < 4; ++t) {
      af[t]  = *(const bf16x8*)(As + (wr * 64 + t * 16 + lq) * 32 + lk * 8);
      bfr[t] = *(const bf16x8*)(Bs + (wc * 64 + t * 16 + lq) * 32 + lk * 8);
    }
#pragma unroll
    for (int mt = 0; mt < 4; ++mt)
#pragma unroll
      for (int nt = 0; nt < 4; ++nt)
        acc[mt][nt] = __builtin_amdgcn_mfma_f32_16x16x32_bf16(af[mt], bfr[nt], acc[mt][nt], 0, 0, 0);
    __syncthreads();
  }

  const int colb = bx * 128 + wc * 64;  // global output column base
  float bcol[4];
#pragma unroll
  for (int nt = 0; nt < 4; ++nt) bcol[nt] = bias[colb + nt * 16 + lq];

  if (MODE == 0) {
    bf16_t* base = (bx < 6) ? Cq : (bx < 12 ? Ck : Cv);
    const int coll = colb - (bx < 6 ? 0 : (bx < 12 ? 768 : 1536));
    if (bx < 12) {
      // RoPE: 32-col chunk pair (nt0,nt1) = axis a0, (nt2,nt3) = axis a1.
      // (colb % 96 is section-invariant since 768 % 96 == 0.)
      const int a0 = (colb % 96) >> 5;
      const int a1 = ((colb + 32) % 96) >> 5;
      const float fr = exp2f(-0.41524101186f * (float)lq);  // 100^(-lq/16)
#pragma unroll
      for (int mt = 0; mt < 4; ++mt) {
        const int rowb = by * 128 + wr * 64 + mt * 16 + lk * 4;
#pragma unroll
        for (int r = 0; r < 4; ++r) {
          const int row = rowb + r;
          float s0, c0, s1, c1;
          __sincosf(posf[row * 3 + a0] * fr, &s0, &c0);
          __sincosf(posf[row * 3 + a1] * fr, &s1, &c1);
          const float x1 = acc[mt][0][r] + bcol[0], x2 = acc[mt][1][r] + bcol[1];
          const float y1 = acc[mt][2][r] + bcol[2], y2 = acc[mt][3][r] + bcol[3];
          acc[mt][0][r] = x1 * c0 - x2 * s0;
          acc[mt][1][r] = x1 * s0 + x2 * c0;
          acc[mt][2][r] = y1 * c1 - y2 * s1;
          acc[mt][3][r] = y1 * s1 + y2 * c1;
        }
#pragma unroll
        for (int nt = 0; nt < 4; ++nt) {
          const int col = coll + nt * 16 + lq;
#pragma unroll
          for (int r = 0; r < 4; ++r)
            base[(size_t)(rowb + r) * 768 + col] = (bf16_t)acc[mt][nt][r];
        }
      }
    } else {
#pragma unroll
      for (int mt = 0; mt < 4; ++mt) {
        const int rowb = by * 128 + wr * 64 + mt * 16 + lk * 4;
#pragma unroll
        for (int nt = 0; nt < 4; ++nt) {
          const int col = coll + nt * 16 + lq;
#pragma unroll
          for (int r = 0; r < 4; ++r)
            base[(size_t)(rowb + r) * 768 + col] = (bf16_t)(acc[mt][nt][r] + bcol[nt]);
        }
      }
    }
  } else {
#pragma unroll
    for (int mt = 0; mt < 4; ++mt) {
      const int rowb = by * 128 + wr * 64 + mt * 16 + lk * 4;
      int ro[4];
#pragma unroll
      for (int r = 0; r < 4; ++r) ro[r] = order[rowb + r];
#pragma unroll
      for (int nt = 0; nt < 4; ++nt) {
        const int col = colb + nt * 16 + lq;
#pragma unroll
        for (int r = 0; r < 4; ++r)
          Cf[(size_t)ro[r] * 768 + col] = acc[mt][nt][r] + bcol[nt];
      }
    }
  }
}

// ---------------- pack: Kb/Vb (roped, row-major) -> MFMA-frag Kp/Vp ------------
// Kp chunk c = (nt*3+a)*64 + lkf*16 + tok15  holds  K[nt*16+tok15][a*32+lkf*8 ..+7]
//   -> a pure 16B-chunk permutation (contiguous feats), coalesced stores.
// Vp chunk c = (dt*8+kc)*64 + lkv*16 + d15   holds  V[kc*32+lkv*8 ..+7][dt*16+d15]
//   -> token-major in j; transpose through padded LDS.
__global__ __launch_bounds__(256) void pack_k(const bf16_t* __restrict__ Kb,
                                              const bf16_t* __restrict__ Vb,
                                              bf16_t* __restrict__ Kp,
                                              bf16_t* __restrict__ Vp) {
  __shared__ bf16_t VT[96 * 264];  // [feat][token], +8 pad: conflict-free both ways
  const int h = blockIdx.x, p = blockIdx.y;
  const int tid = threadIdx.x;
  const int tok0 = p * 256;
  const size_t phb = (size_t)(p * 8 + h) * 24576;

  // K: 16B-chunk permutation
#pragma unroll
  for (int i = 0; i < 12; ++i) {
    const int c = i * 256 + tid;
    const int fi = c >> 6, ln = c & 63;
    const int nt = fi / 3, a = fi - nt * 3;
    const int tok = nt * 16 + (ln & 15), feat = a * 32 + (ln >> 4) * 8;
    *(bf16x8*)(Kp + phb + (size_t)c * 8) =
        *(const bf16x8*)(Kb + (size_t)(tok0 + tok) * 768 + h * 96 + feat);
  }

  // V: stage transposed into LDS (u16 writes: lanes consecutive -> conflict-free)
  {
    const bf16_t* vrow = Vb + (size_t)(tok0 + tid) * 768 + h * 96;
#pragma unroll
    for (int d0 = 0; d0 < 96; d0 += 8) {
      bf16x8 v = *(const bf16x8*)(vrow + d0);
#pragma unroll
      for (int i = 0; i < 8; ++i) VT[(d0 + i) * 264 + tid] = v[i];
    }
  }
  __syncthreads();
  // V: frag chunks = 8 consecutive tokens @ fixed feat = b128 from VT, coalesced out
#pragma unroll
  for (int i = 0; i < 12; ++i) {
    const int c = i * 256 + tid;
    const int fi = c >> 6, ln = c & 63;  // fi = dt*8+kc
    const int d = (fi >> 3) * 16 + (ln & 15);
    const int tb = (fi & 7) * 32 + (ln >> 4) * 8;
    *(bf16x8*)(Vp + phb + (size_t)c * 8) = *(const bf16x8*)(VT + d * 264 + tb);
  }
}

// ---------------- windowed attention (v4: LDS-staged K then V) -----------------
// grid = ph*4 chunks; block = 4 waves, each owns 16 q-rows of one (p,h).
// Stage Kp slice (48KB) -> LDS, S from ds_read_b128; barrier; restage Vp slice
// into the SAME 48KB (overlapped with softmax); PV through a per-wave PRIVATE
// 4KB XOR-swizzled P buffer in two 128-token halves.  LDS = 64KB exactly.
__global__ __launch_bounds__(256) void attn_k(bf16_t* QO,   // Q in, O out (same buffer)
                                              const bf16_t* __restrict__ Kp,
                                              const bf16_t* __restrict__ Vp) {
  __shared__ bf16_t KV[24576];     // 48KB: K frags, then V frags
  __shared__ bf16_t Pb[4][2048];   // 16KB: per-wave swizzled 16x128 P half
  const int bid = blockIdx.x;
  const int chunk = bid & 3;
  const int ph = bid >> 2;
  const int h = ph & 7, p = ph >> 3;
  const int tid = threadIdx.x, lane = tid & 63, wave = tid >> 6;
  const int lq = lane & 15, lk = lane >> 4;
  const int tok0 = p * 256;
  const int qrow0 = chunk * 64 + wave * 16;
  const bf16_t* Kps = Kp + (size_t)ph * 24576;
  const bf16_t* Vps = Vp + (size_t)ph * 24576;
  const float scale = 0.10206207262f;  // 96^-0.5

  // ---- stage K frags (48KB) async; Q frag loads overlap
#pragma unroll
  for (int i = 0; i < 12; ++i)
    gload_lds16(Kps + i * 2048 + tid * 8, KV + i * 2048 + tid * 8);
  bf16x8 aq[3];
  {
    const bf16_t* qb = QO + (size_t)(tok0 + qrow0 + lq) * 768 + h * 96 + lk * 8;
#pragma unroll
    for (int kc = 0; kc < 3; ++kc) aq[kc] = *(const bf16x8*)(qb + kc * 32);
  }
  __syncthreads();

  // ---- S = Q.K^T from LDS
  f32x4 sacc[16];
#pragma unroll
  for (int nt = 0; nt < 16; ++nt) {
    f32x4 acc = {0.f, 0.f, 0.f, 0.f};
#pragma unroll
    for (int kc = 0; kc < 3; ++kc) {
      bf16x8 bk = *(const bf16x8*)(KV + (size_t)((nt * 3 + kc) * 64 + lane) * 8);
      acc = __builtin_amdgcn_mfma_f32_16x16x32_bf16(aq[kc], bk, acc, 0, 0, 0);
    }
    sacc[nt] = acc;
  }
  __syncthreads();   // all waves done reading K from LDS

  // ---- restage V frags into same LDS (async; overlaps softmax VALU)
#pragma unroll
  for (int i = 0; i < 12; ++i)
    gload_lds16(Vps + i * 2048 + tid * 8, KV + i * 2048 + tid * 8);

  // ---- softmax (rows in C-layout: row = lk*4+r, col = nt*16+lq)
  float linv[4];
#pragma unroll
  for (int r = 0; r < 4; ++r) {
    float mx = -1e30f;
#pragma unroll
    for (int nt = 0; nt < 16; ++nt) mx = fmaxf(mx, sacc[nt][r]);
    mx = fmaxf(mx, __shfl_xor(mx, 1));
    mx = fmaxf(mx, __shfl_xor(mx, 2));
    mx = fmaxf(mx, __shfl_xor(mx, 4));
    mx = fmaxf(mx, __shfl_xor(mx, 8));
    mx *= scale;
    float l = 0.f;
#pragma unroll
    for (int nt = 0; nt < 16; ++nt) {
      float e = __expf(sacc[nt][r] * scale - mx);
      sacc[nt][r] = e;
      l += e;
    }
    l += __shfl_xor(l, 1);
    l += __shfl_xor(l, 2);
    l += __shfl_xor(l, 4);
    l += __shfl_xor(l, 8);
    linv[r] = 1.f / l;
  }
  __syncthreads();   // V staged

  // ---- PV in two 128-token halves through private swizzled P buffer.
  // Same-wave DS ops are in-order, so no barrier needed around Pb.
  bf16_t* pw = &Pb[wave][0];
  f32x4 oacc[6] = {};
#pragma unroll
  for (int hf = 0; hf < 2; ++hf) {
#pragma unroll
    for (int ntl = 0; ntl < 8; ++ntl) {
      const int nt = hf * 8 + ntl;
      const int chk = ntl * 2 + (lq >> 3);
#pragma unroll
      for (int r = 0; r < 4; ++r) {
        const int row = lk * 4 + r;
        const int phys = chk ^ (row & 7);
        pw[row * 128 + phys * 8 + (lq & 7)] = (bf16_t)sacc[nt][r];
      }
    }
#pragma unroll
    for (int kcl = 0; kcl < 4; ++kcl) {
      const int physr = (kcl * 4 + lk) ^ (lq & 7);
      bf16x8 pf = *(const bf16x8*)(pw + lq * 128 + physr * 8);
      const int kc = hf * 4 + kcl;
#pragma unroll
      for (int dt = 0; dt < 6; ++dt) {
        bf16x8 vb = *(const bf16x8*)(KV + (size_t)((dt * 8 + kc) * 64 + lane) * 8);
        oacc[dt] = __builtin_amdgcn_mfma_f32_16x16x32_bf16(pf, vb, oacc[dt], 0, 0, 0);
      }
    }
  }

  // ---- write O over Q (same rows this wave read; safe in-place)
#pragma unroll
  for (int dt = 0; dt < 6; ++dt) {
#pragma unroll
    for (int r = 0; r < 4; ++r) {
      const int row = tok0 + qrow0 + lk * 4 + r;
      QO[(size_t)row * 768 + h * 96 + dt * 16 + lq] = (bf16_t)(oacc[dt][r] * linv[r]);
    }
  }
}

extern "C" void kernel_launch(void* const* d_in, const int* in_sizes, int n_in,
                              void* d_out, int out_size, void* d_ws, size_t ws_size,
                              hipStream_t stream) {
  const float* feat       = (const float*)d_in[0];
  const int*   grid_coord = (const int*)d_in[1];
  const int*   order      = (const int*)d_in[2];
  // d_in[3] = inverse (unused: scatter-by-order is equivalent)
  const float* w_qkv      = (const float*)d_in[4];
  const float* b_qkv      = (const float*)d_in[5];
  const float* w_proj     = (const float*)d_in[6];
  const float* b_proj     = (const float*)d_in[7];
  float* out = (float*)d_out;

  char* ws = (char*)d_ws;
  bf16_t* Bt1   = (bf16_t*)(ws);                 // 2304x768  bf16  (3,538,944 B)
  bf16_t* Bt2   = (bf16_t*)(ws + 3538944);       // 768x768   bf16  (1,179,648 B)
  bf16_t* featp = (bf16_t*)(ws + 4718592);       // 32768x768 bf16  (50,331,648 B)
  bf16_t* Kp    = featp;                         // featp dead after gemm1; reuse for Kp
  bf16_t* Qb    = (bf16_t*)(ws + 55050240);      // 32768x768 bf16
  bf16_t* Kb    = (bf16_t*)(ws + 105381888);     // 32768x768 bf16
  bf16_t* Vb    = (bf16_t*)(ws + 155713536);     // 32768x768 bf16
  bf16_t* Vp    = (bf16_t*)(ws + 206045184);     // 1024x24576 bf16 (50,331,648 B)
  float*  posf  = (float*)(ws + 206045184);      // 32768x3 fp32 — aliases Vp:
  // posf lives gather->gemm1; Vp lives pack->attn; lifetimes are disjoint.

  transpose_cast_k<<<dim3(36, 12), 256, 0, stream>>>(w_qkv, Bt1, 768, 2304);
  transpose_cast_k<<<dim3(12, 12), 256, 0, stream>>>(w_proj, Bt2, 768, 768);
  gather_cast_k<<<24576, 256, 0, stream>>>(feat, order, grid_coord, featp, posf);
  gemm_bt_k<0><<<dim3(18, 256), 256, 0, stream>>>(featp, Bt1, b_qkv, Qb, Kb, Vb, nullptr, nullptr, posf);
  pack_k<<<dim3(8, 128), 256, 0, stream>>>(Kb, Vb, Kp, Vp);
  attn_k<<<4096, 256, 0, stream>>>(Qb, Kp, Vp);
  gemm_bt_k<1><<<dim3(6, 256), 256, 0, stream>>>(Qb, Bt2, b_proj, nullptr, nullptr, nullptr, out, order, nullptr);
}